// Round 11
// baseline (199.420 us; speedup 1.0000x reference)
//
#include <hip/hip_runtime.h>

// ---------------------------------------------------------------------------
// DeepCapsNet forward. R22: R21 + caps-tail phase optimization:
//  - Sv/PV phases: 2 threads per element (16 serial i each) + shfl_xor(1)
//    combine (was 32 serial LDS reads on 256/512 threads).
//  - Av phase: float4 LDS reads (2-4 b128 instead of 8-16 scalar).
//  - softmax: 16 lanes/row -> all 512 threads active.
// conv2 core unchanged from R18/R21 (4 waves/SIMD, B j-half split).
// Workspace layout (dwords):
//   Bt : [131072, 425984)   u32 [sidx][cot][hi/lo][n=128][16dw]
//   w3T: [425984, 446720)   f32 [p=81][c=256]
//   Wr1: [446720, 512256)   f32 [(ik,l)][j=8] contiguous-j
//   Wr2: [512256, 577792)   f32
//   Wr3: [577792, 618752)   f32
//   sc1: [618752, 619008)   float2[128] bn1 scale/shift (conv1 bias folded)
// ---------------------------------------------------------------------------

typedef __attribute__((ext_vector_type(8))) short short8;   // 8 bf16
typedef __attribute__((ext_vector_type(4))) float f32x4;

__device__ __forceinline__ ushort f2bf(float x) {
    uint u = __float_as_uint(x);
    return (ushort)((u + 0x7FFFu + ((u >> 16) & 1u)) >> 16);
}
__device__ __forceinline__ void bfsplit(float x, ushort& h, ushort& l) {
    h = f2bf(x);
    float hf = __uint_as_float(((uint)h) << 16);
    l = f2bf(x - hf);
}

// ---------------- merged prep: Bt + w3T + Wr + sc1 ------------------------
__global__ __launch_bounds__(256) void k_prep(
    const float* __restrict__ w2, uint* __restrict__ Bt,
    const float* __restrict__ w3, float* __restrict__ w3T,
    const float* __restrict__ W1, const float* __restrict__ W2,
    const float* __restrict__ W3, float* __restrict__ Wr1,
    float* __restrict__ Wr2, float* __restrict__ Wr3,
    const float* __restrict__ c1b, const float* __restrict__ g1,
    const float* __restrict__ b1, const float* __restrict__ m1,
    const float* __restrict__ v1, float2* __restrict__ sc1) {
    __shared__ __align__(16) float wbuf[64 * 288];
    const int b = blockIdx.x, t = threadIdx.x;
    if (b < 144) {            // ---- Bt: [sidx][cot][hi/lo][n=128][16dw]
        const int sidx = b >> 2, coq = b & 3;
        const int chunk = sidx / 9, tap = sidx - chunk * 9;
        const int co0 = coq * 64;
        for (int idx = t; idx < 4608; idx += 256) {
            const int n = idx / 72, q = idx - n * 72;
            ((float4*)wbuf)[n * 72 + q] =
                *(const float4*)(w2 + (size_t)(co0 + n) * 1152 + chunk * 288 + q * 4);
        }
        __syncthreads();
        const int n = t & 63, dg = (t >> 6) * 4;
        const int cot = coq >> 1, nn = ((coq & 1) * 64) + n;
        uint* dst = Bt + (size_t)(sidx * 2 + cot) * 4096;
#pragma unroll
        for (int dd = 0; dd < 4; ++dd) {
            const int d = dg + dd;
            const float x = wbuf[n * 288 + (2 * d) * 9 + tap];
            const float y = wbuf[n * 288 + (2 * d + 1) * 9 + tap];
            ushort xh, xl, yh, yl;
            bfsplit(x, xh, xl);
            bfsplit(y, yh, yl);
            dst[nn * 16 + d]        = (uint)xh | ((uint)yh << 16);
            dst[2048 + nn * 16 + d] = (uint)xl | ((uint)yl << 16);
        }
    } else if (b < 225) {     // ---- w3T
        const int p = b - 144;
        w3T[p * 256 + t] = w3[t * 81 + p];
    } else if (b < 321) {     // ---- Wr: [(ik,l)][j] contiguous-j layout
        const int bb = b - 225;
        const int layer = bb >> 5, blk = bb & 31;
        const float* src = layer == 0 ? W1 : (layer == 1 ? W2 : W3);
        float* dst = layer == 0 ? Wr1 : (layer == 1 ? Wr2 : Wr3);
        const int d_h = (layer == 2) ? 16 : 8;
        const int total = (layer == 2) ? 5120 : 8192;
        for (int idx = blk * 256 + t; idx < 8 * total; idx += 32 * 256) {
            const int e = idx >> 3, j = idx & 7;
            const int ik = e / d_h, l = e - ik * d_h;
            dst[idx] = src[(ik * 8 + j) * d_h + l];
        }
    } else {                  // ---- sc1: bn1 scale/shift with conv1 bias folded
        if (t < 128) {
            const float inv = g1[t] * rsqrtf(v1[t] + 1e-5f);
            sc1[t] = make_float2(inv, c1b[t] * inv + b1[t] - m1[t] * inv);
        }
    }
}

// ---------------- fccaps on 512 threads, LDS-resident ----------------------
__device__ __forceinline__ void fccaps512(
    const int n_l, const int n_h, const int d_h, const float* __restrict__ Wr,
    float* U, float* Uh, float* Sv, float* Av, float* Cv, float* coefs,
    float* outU, const int t) {
    const int nkd = n_h * d_h;
    const int total = n_l * nkd;
    __syncthreads();
    for (int e = t; e < total; e += 512) {       // U_hat: 2x dwordx4 per elem
        const int i = e / nkd;
        const float4* w4 = (const float4*)(Wr + (size_t)e * 8);
        const float4 wa = w4[0], wb = w4[1];
        const float4* u4 = (const float4*)(U + i * 8);
        const float4 ua = u4[0], ub = u4[1];
        Uh[e] = ua.x * wa.x + ua.y * wa.y + ua.z * wa.z + ua.w * wa.w +
                ub.x * wb.x + ub.y * wb.y + ub.z * wb.z + ub.w * wb.w;
    }
    __syncthreads();
    {   // Sv: 2 threads per elem, 16 i each, shfl combine
        const int e = t >> 1, i0 = (t & 1) * (n_l / 2);
        float acc = 0.0f;
        if (e < nkd)
            for (int i = i0; i < i0 + n_l / 2; ++i) acc += Uh[i * nkd + e];
        acc += __shfl_xor(acc, 1);
        if (e < nkd && (t & 1) == 0) Sv[e] = acc;
    }
    __syncthreads();
    for (int e = t; e < n_l * n_h; e += 512) {   // Av: float4 reads
        const int h = e / n_h, k = e - h * n_h;
        const float4* uh4 = (const float4*)(Uh + h * nkd + k * d_h);
        const float4* sv4 = (const float4*)(Sv + k * d_h);
        float acc = 0.0f;
#pragma unroll
        for (int q = 0; q < 4; ++q) {
            if (q < d_h / 4) {
                const float4 a = uh4[q], b = sv4[q];
                acc += a.x * b.x + a.y * b.y + a.z * b.z + a.w * b.w;
            }
        }
        Av[e] = acc;
    }
    __syncthreads();
    {   // softmax over k: 16 lanes per row h (h = t>>4 covers 32 rows)
        const int h = t >> 4, sub = t & 15;
        const float invs = 1.0f / 2.8284271247461903f;
        float mx = -1e30f;
        for (int k = sub; k < n_h; k += 16) mx = fmaxf(mx, Av[h * n_h + k]);
        mx = fmaxf(mx, __shfl_xor(mx, 1));
        mx = fmaxf(mx, __shfl_xor(mx, 2));
        mx = fmaxf(mx, __shfl_xor(mx, 4));
        mx = fmaxf(mx, __shfl_xor(mx, 8));
        float sum = 0.0f;
        for (int k = sub; k < n_h; k += 16) {
            const float ev = expf((Av[h * n_h + k] - mx) * invs);
            Cv[h * n_h + k] = ev;
            sum += ev;
        }
        sum += __shfl_xor(sum, 1);
        sum += __shfl_xor(sum, 2);
        sum += __shfl_xor(sum, 4);
        sum += __shfl_xor(sum, 8);
        const float r = 1.0f / sum;
        for (int k = sub; k < n_h; k += 16) Cv[h * n_h + k] *= r;
    }
    __syncthreads();
    {   // PV: 2 threads per elem, 16 i each, shfl combine
        const int e = t >> 1, i0 = (t & 1) * (n_l / 2);
        float acc = 0.0f;
        if (e < nkd) {
            const int k = e / d_h;
            for (int i = i0; i < i0 + n_l / 2; ++i)
                acc += Uh[i * nkd + e] * Cv[i * n_h + k];
        }
        acc += __shfl_xor(acc, 1);
        if (e < nkd && (t & 1) == 0) Sv[e] = acc;
    }
    __syncthreads();
    if (t < n_h) {
        float ssq = 0.0f;
        for (int l = 0; l < d_h; ++l) { const float uv = Sv[t * d_h + l]; ssq += uv * uv; }
        const float n = sqrtf(ssq);
        coefs[t] = (1.0f - 1.0f / (expf(n) + 1e-20f)) / (n + 1e-20f);
    }
    __syncthreads();
    for (int e = t; e < nkd; e += 512) outU[e] = Sv[e] * coefs[e / d_h];
}

// ---------------- conv1+conv2+conv3+caps fused, one block per image --------
__global__ __launch_bounds__(512, 4) void k_conv2(
    const float* __restrict__ x, const float* __restrict__ w1,
    const float2* __restrict__ sc1, const uint* __restrict__ Bt,
    const float* __restrict__ g,
    const float* __restrict__ bb, const float* __restrict__ bm,
    const float* __restrict__ bv, const float* __restrict__ bias,
    const float* __restrict__ w3T, const float* __restrict__ b3,
    const float* __restrict__ Wr1, const float* __restrict__ Wr2,
    const float* __restrict__ Wr3, float* __restrict__ out) {
    __shared__ __align__(16) uint raw[11552];
    __shared__ __align__(16) float xs[1560];   // [39][40] padded stride
    __shared__ float ured[256];
    const int t = threadIdx.x;
    const int lane = t & 63, wave = t >> 6;          // wave 0..7
    const int ln15 = lane & 15, lq = lane >> 4;
    const int wm = (wave >> 2) * 48;                 // 0 | 48
    const int wn = (wave & 3) * 64;                  // 0 | 64 | 128 | 192
    const int cot_w = (wave & 3) >> 1;               // Bt cot block for this wave
    const int bi = blockIdx.x;

    // stage the input image into padded [39][40] layout (once per image)
    const float* xb = x + (size_t)bi * 1521;
    for (int i = t; i < 1521; i += 512) {
        const int y = i / 39, xc = i - y * 39;
        xs[y * 40 + xc] = xb[i];
    }

    // conv1 thread mapping: qc -> channel pair (2 ch), pg -> positions
    const int qc = t & 15, ol = qc >> 2, qo = (qc & 3) * 2, pg = t >> 4;

    int PE[3], PO[3];
#pragma unroll
    for (int i = 0; i < 3; ++i) {
        const int m = wm + i * 16 + ln15;
        const int p = m < 81 ? m : 80;       // pad rows clamp
        const int oh = p / 9, ow = p - oh * 9;
        PE[i] = lq * 760 + oh * 80 + ow * 4;
        PO[i] = 3040 + lq * 684 + oh * 72 + ow * 4;
    }
    int BRDg[4];
#pragma unroll
    for (int j = 0; j < 4; ++j) {
        const int n = ((wn & 64) + j * 16 + ln15);   // row within cot block
        BRDg[j] = n * 16 + lq * 4;
    }

    f32x4 acc[3][4] = {};

#pragma unroll
    for (int c = 0; c < 4; ++c) {
        // ---- conv1 weight/bn prefetch for this chunk (no LDS dependency) --
        const int o_g = c * 32 + qc * 2;     // global channel of this pair
        float wr[18];
        {
            const float2* wp = reinterpret_cast<const float2*>(w1 + o_g * 9);
#pragma unroll
            for (int q = 0; q < 9; ++q) {
                const float2 wv = wp[q];
                wr[q * 2] = wv.x; wr[q * 2 + 1] = wv.y;
            }
        }
        float2 ssv[2];
        ssv[0] = sc1[o_g];
        ssv[1] = sc1[o_g + 1];

        __syncthreads();   // prev chunk's MFMA reads done (and xs ready at c=0)

        // ---- conv1: 2 channels x ~11 positions into raw (LDS) -------------
        {
            ushort* rawu = (ushort*)raw;
            for (int p = pg; p < 361; p += 32) {
                const int y = p / 19, xq = p - y * 19;
                const int b2 = y * 80 + xq * 2;
                const float2 x01 = *(const float2*)(xs + b2);
                const float  x2v = xs[b2 + 2];
                const float2 x34 = *(const float2*)(xs + b2 + 40);
                const float  x5v = xs[b2 + 42];
                const float2 x67 = *(const float2*)(xs + b2 + 80);
                const float  x8v = xs[b2 + 82];
                uint hw, lw;
                {
                    uint hv[2], lv[2];
#pragma unroll
                    for (int jj = 0; jj < 2; ++jj) {
                        const float a = x01.x * wr[jj * 9 + 0] + x01.y * wr[jj * 9 + 1] +
                                        x2v   * wr[jj * 9 + 2] + x34.x * wr[jj * 9 + 3] +
                                        x34.y * wr[jj * 9 + 4] + x5v   * wr[jj * 9 + 5] +
                                        x67.x * wr[jj * 9 + 6] + x67.y * wr[jj * 9 + 7] +
                                        x8v   * wr[jj * 9 + 8];
                        const float v = fmaxf(fmaf(a, ssv[jj].x, ssv[jj].y), 0.0f);
                        const uint u = __float_as_uint(v);
                        hv[jj] = u >> 16;                               // trunc hi
                        const float d = v - __uint_as_float(u & 0xFFFF0000u);
                        lv[jj] = __float_as_uint(d) >> 16;              // trunc lo
                    }
                    hw = hv[0] | (hv[1] << 16);
                    lw = lv[0] | (lv[1] << 16);
                }
                int ad;
                if ((xq & 1) == 0) {
                    ad = ol * 1520 + (y * 10 + (xq >> 1)) * 8 + qo;
                } else {
                    ad = 6080 + ol * 1368 + (y * 9 + (xq >> 1)) * 8 + qo;
                }
                *(uint*)(rawu + ad)         = hw;
                *(uint*)(rawu + 11552 + ad) = lw;
            }
        }
        __syncthreads();

        // ---- r7 MFMA tap loop: B processed in two j-halves (R18) ---------
#pragma unroll
        for (int tap = 0; tap < 9; ++tap) {
            const int s = c * 9 + tap;
            const int kh = tap / 3, kw = tap - kh * 3;
            const int odd = kw & 1;
            const int sE = kh * 40 + (kw >> 1) * 4;
            const int sO = kh * 36;
            short8 a_h[3], a_l[3];
#pragma unroll
            for (int i = 0; i < 3; ++i) {
                const int addr = odd ? (PO[i] + sO) : (PE[i] + sE);
                a_h[i] = *reinterpret_cast<const short8*>(raw + addr);
                a_l[i] = *reinterpret_cast<const short8*>(raw + addr + 5776);
            }
            const uint* bp = Bt + (size_t)(s * 2 + cot_w) * 4096;
#pragma unroll
            for (int jh = 0; jh < 2; ++jh) {
                uint4 Bc[4];
#pragma unroll
                for (int j2 = 0; j2 < 2; ++j2) {
                    Bc[j2]     = *(const uint4*)(bp + BRDg[jh * 2 + j2]);
                    Bc[2 + j2] = *(const uint4*)(bp + 2048 + BRDg[jh * 2 + j2]);
                }
                short8 bh[2], bl[2];
#pragma unroll
                for (int j2 = 0; j2 < 2; ++j2) {
                    bh[j2] = __builtin_bit_cast(short8, Bc[j2]);
                    bl[j2] = __builtin_bit_cast(short8, Bc[2 + j2]);
                }
#pragma unroll
                for (int i = 0; i < 3; ++i)
#pragma unroll
                    for (int j2 = 0; j2 < 2; ++j2)
                        acc[i][jh * 2 + j2] = __builtin_amdgcn_mfma_f32_16x16x32_bf16(
                            a_h[i], bh[j2], acc[i][jh * 2 + j2], 0, 0, 0);
#pragma unroll
                for (int i = 0; i < 3; ++i)
#pragma unroll
                    for (int j2 = 0; j2 < 2; ++j2)
                        acc[i][jh * 2 + j2] = __builtin_amdgcn_mfma_f32_16x16x32_bf16(
                            a_h[i], bl[j2], acc[i][jh * 2 + j2], 0, 0, 0);
#pragma unroll
                for (int i = 0; i < 3; ++i)
#pragma unroll
                    for (int j2 = 0; j2 < 2; ++j2)
                        acc[i][jh * 2 + j2] = __builtin_amdgcn_mfma_f32_16x16x32_bf16(
                            a_l[i], bh[j2], acc[i][jh * 2 + j2], 0, 0, 0);
            }
        }
    }

    // ---- epilogue: bn + relu + fused depthwise conv3 reduction ------------
    float scj[4], shj[4];
#pragma unroll
    for (int j = 0; j < 4; ++j) {
        const int co = wn + j * 16 + ln15;
        const float inv = g[co] * rsqrtf(bv[co] + 1e-5f);
        scj[j] = inv;
        shj[j] = bias[co] * inv + bb[co] - bm[co] * inv;
    }
    float usum[4] = {0.f, 0.f, 0.f, 0.f};
#pragma unroll
    for (int i = 0; i < 3; ++i)
#pragma unroll
        for (int r = 0; r < 4; ++r) {
            const int m = wm + i * 16 + lq * 4 + r;
            if (m < 81) {
                const float* wrow = w3T + m * 256;
#pragma unroll
                for (int j = 0; j < 4; ++j) {
                    const int col = wn + j * 16 + ln15;
                    const float v = fmaxf(fmaf(acc[i][j][r], scj[j], shj[j]), 0.0f);
                    usum[j] = fmaf(v, wrow[col], usum[j]);
                }
            }
        }
#pragma unroll
    for (int j = 0; j < 4; ++j) {
        usum[j] += __shfl_xor(usum[j], 16);
        usum[j] += __shfl_xor(usum[j], 32);
    }
    if (lq == 0 && wm == 0) {
#pragma unroll
        for (int j = 0; j < 4; ++j) ured[wn + j * 16 + ln15] = usum[j];
    }
    __syncthreads();   // ured ready; tap-loop reads of raw long done

    // ---- caps scratch aliased onto raw ------------------------------------
    float* cF    = (float*)raw;          // capsU: [0,256)
    float* Uh    = cF + 256;             // [256, 8448)
    float* Sv    = cF + 8448;            // [8448, 8704)
    float* Av    = cF + 8704;            // [8704, 9728)
    float* Cv    = cF + 9728;            // [9728, 10752)
    float* coefs = cF + 10752;           // [10752, 10784)

    if (lq == 0 && wm == 48) {
#pragma unroll
        for (int j = 0; j < 4; ++j) {
            const int col = wn + j * 16 + ln15;
            cF[col] = usum[j] + ured[col] + b3[col];
        }
    }
    __syncthreads();
    if (t < 32) {   // initial squash over 32 caps of 8
        float ssq = 0.0f;
        for (int j = 0; j < 8; ++j) { const float uv = cF[t * 8 + j]; ssq += uv * uv; }
        const float n = sqrtf(ssq);
        coefs[t] = (1.0f - 1.0f / (expf(n) + 1e-20f)) / (n + 1e-20f);
    }
    __syncthreads();
    if (t < 256) cF[t] *= coefs[t >> 3];

    fccaps512(32, 32,  8, Wr1, cF, Uh, Sv, Av, Cv, coefs, cF, t);
    fccaps512(32, 32,  8, Wr2, cF, Uh, Sv, Av, Cv, coefs, cF, t);
    fccaps512(32, 10, 16, Wr3, cF, Uh, Sv, Av, Cv, coefs, out + (size_t)bi * 160, t);
}

// ---------------------------------------------------------------------------
extern "C" void kernel_launch(void* const* d_in, const int* in_sizes, int n_in,
                              void* d_out, int out_size, void* d_ws, size_t ws_size,
                              hipStream_t stream) {
    const float* x    = (const float*)d_in[0];
    const float* c1w  = (const float*)d_in[1];
    const float* c1b  = (const float*)d_in[2];
    const float* bn1g = (const float*)d_in[3];
    const float* bn1b = (const float*)d_in[4];
    const float* bn1m = (const float*)d_in[5];
    const float* bn1v = (const float*)d_in[6];
    const float* c2w  = (const float*)d_in[7];
    const float* c2b  = (const float*)d_in[8];
    const float* bn2g = (const float*)d_in[9];
    const float* bn2b = (const float*)d_in[10];
    const float* bn2m = (const float*)d_in[11];
    const float* bn2v = (const float*)d_in[12];
    const float* c3w  = (const float*)d_in[13];
    const float* c3b  = (const float*)d_in[14];
    const float* W1   = (const float*)d_in[15];
    const float* W2   = (const float*)d_in[16];
    const float* W3   = (const float*)d_in[17];
    float* out = (float*)d_out;
    uint*  wsu = (uint*)d_ws;
    float* wsf = (float*)d_ws;

    uint*   Bt  = wsu + 131072;            //    294,912 dw
    float*  w3T = wsf + 425984;            //     20,736 dw
    float*  Wr1 = wsf + 446720;            //     65,536 dw
    float*  Wr2 = wsf + 512256;            //     65,536 dw
    float*  Wr3 = wsf + 577792;            //     40,960 dw
    float2* sc1 = (float2*)(wsf + 618752); //        256 dw

    k_prep<<<dim3(322), 256, 0, stream>>>(c2w, Bt, c3w, w3T, W1, W2, W3,
                                          Wr1, Wr2, Wr3,
                                          c1b, bn1g, bn1b, bn1m, bn1v, sc1);
    k_conv2<<<dim3(512), 512, 0, stream>>>(x, c1w, sc1, Bt,
                                           bn2g, bn2b, bn2m, bn2v,
                                           c2b, w3T, c3b, Wr1, Wr2, Wr3, out);
}

// Round 12
// 196.530 us; speedup vs baseline: 1.0147x; 1.0147x over previous
//
#include <hip/hip_runtime.h>

// ---------------------------------------------------------------------------
// DeepCapsNet forward. R23: caps tail reverted to R21 form (R22's phase
// parallelization regressed: +0.7M bank conflicts, +3MB spill, +3.6us) plus
// one subtraction-only change: squash scaling FOLDED into next layer's
// U_hat (U_hat[e] = coef[i]*(V[i]&middot;W[e]) — exact to ~1ulp). Deletes the
// outU phase+barrier for layers 1->2, 2->3 and the initial cF*=coefs pass:
// 3 phases, 3 barriers, ~770 LDS R/W removed, zero instructions added to
// hot paths. conv2 core unchanged from R18/R21.
// Workspace layout (dwords):
//   Bt : [131072, 425984)   u32 [sidx][cot][hi/lo][n=128][16dw]
//   w3T: [425984, 446720)   f32 [p=81][c=256]
//   Wr1: [446720, 512256)   f32 [(ik,l)][j=8] contiguous-j
//   Wr2: [512256, 577792)   f32
//   Wr3: [577792, 618752)   f32
//   sc1: [618752, 619008)   float2[128] bn1 scale/shift (conv1 bias folded)
// ---------------------------------------------------------------------------

typedef __attribute__((ext_vector_type(8))) short short8;   // 8 bf16
typedef __attribute__((ext_vector_type(4))) float f32x4;

__device__ __forceinline__ ushort f2bf(float x) {
    uint u = __float_as_uint(x);
    return (ushort)((u + 0x7FFFu + ((u >> 16) & 1u)) >> 16);
}
__device__ __forceinline__ void bfsplit(float x, ushort& h, ushort& l) {
    h = f2bf(x);
    float hf = __uint_as_float(((uint)h) << 16);
    l = f2bf(x - hf);
}

// ---------------- merged prep: Bt + w3T + Wr + sc1 ------------------------
__global__ __launch_bounds__(256) void k_prep(
    const float* __restrict__ w2, uint* __restrict__ Bt,
    const float* __restrict__ w3, float* __restrict__ w3T,
    const float* __restrict__ W1, const float* __restrict__ W2,
    const float* __restrict__ W3, float* __restrict__ Wr1,
    float* __restrict__ Wr2, float* __restrict__ Wr3,
    const float* __restrict__ c1b, const float* __restrict__ g1,
    const float* __restrict__ b1, const float* __restrict__ m1,
    const float* __restrict__ v1, float2* __restrict__ sc1) {
    __shared__ __align__(16) float wbuf[64 * 288];
    const int b = blockIdx.x, t = threadIdx.x;
    if (b < 144) {            // ---- Bt: [sidx][cot][hi/lo][n=128][16dw]
        const int sidx = b >> 2, coq = b & 3;
        const int chunk = sidx / 9, tap = sidx - chunk * 9;
        const int co0 = coq * 64;
        for (int idx = t; idx < 4608; idx += 256) {
            const int n = idx / 72, q = idx - n * 72;
            ((float4*)wbuf)[n * 72 + q] =
                *(const float4*)(w2 + (size_t)(co0 + n) * 1152 + chunk * 288 + q * 4);
        }
        __syncthreads();
        const int n = t & 63, dg = (t >> 6) * 4;
        const int cot = coq >> 1, nn = ((coq & 1) * 64) + n;
        uint* dst = Bt + (size_t)(sidx * 2 + cot) * 4096;
#pragma unroll
        for (int dd = 0; dd < 4; ++dd) {
            const int d = dg + dd;
            const float x = wbuf[n * 288 + (2 * d) * 9 + tap];
            const float y = wbuf[n * 288 + (2 * d + 1) * 9 + tap];
            ushort xh, xl, yh, yl;
            bfsplit(x, xh, xl);
            bfsplit(y, yh, yl);
            dst[nn * 16 + d]        = (uint)xh | ((uint)yh << 16);
            dst[2048 + nn * 16 + d] = (uint)xl | ((uint)yl << 16);
        }
    } else if (b < 225) {     // ---- w3T
        const int p = b - 144;
        w3T[p * 256 + t] = w3[t * 81 + p];
    } else if (b < 321) {     // ---- Wr: [(ik,l)][j] contiguous-j layout
        const int bb = b - 225;
        const int layer = bb >> 5, blk = bb & 31;
        const float* src = layer == 0 ? W1 : (layer == 1 ? W2 : W3);
        float* dst = layer == 0 ? Wr1 : (layer == 1 ? Wr2 : Wr3);
        const int d_h = (layer == 2) ? 16 : 8;
        const int total = (layer == 2) ? 5120 : 8192;
        for (int idx = blk * 256 + t; idx < 8 * total; idx += 32 * 256) {
            const int e = idx >> 3, j = idx & 7;
            const int ik = e / d_h, l = e - ik * d_h;
            dst[idx] = src[(ik * 8 + j) * d_h + l];
        }
    } else {                  // ---- sc1: bn1 scale/shift with conv1 bias folded
        if (t < 128) {
            const float inv = g1[t] * rsqrtf(v1[t] + 1e-5f);
            sc1[t] = make_float2(inv, c1b[t] * inv + b1[t] - m1[t] * inv);
        }
    }
}

// ---------------- fccaps on 512 threads, LDS-resident ----------------------
// Input capsules are (Vin, cIn): U[i][j] = Vin[i*8+j] * cIn[i] (squash coef
// folded into U_hat). Output: Sv holds V_out, coefs holds c_out. If outG is
// non-null, also writes outG[e] = Sv[e]*coefs[e/d_h] (final layer).
__device__ __forceinline__ void fccaps512(
    const int n_l, const int n_h, const int d_h, const float* __restrict__ Wr,
    const float* Vin, const float* cIn, float* Uh, float* Sv, float* Av,
    float* Cv, float* coefs, float* outG, const int t) {
    const int nkd = n_h * d_h;
    const int total = n_l * nkd;
    __syncthreads();
    for (int e = t; e < total; e += 512) {       // U_hat: 2x dwordx4 + coef
        const int i = e / nkd;
        const float4* w4 = (const float4*)(Wr + (size_t)e * 8);
        const float4 wa = w4[0], wb = w4[1];
        const float4* u4 = (const float4*)(Vin + i * 8);
        const float4 ua = u4[0], ub = u4[1];
        Uh[e] = cIn[i] *
                (ua.x * wa.x + ua.y * wa.y + ua.z * wa.z + ua.w * wa.w +
                 ub.x * wb.x + ub.y * wb.y + ub.z * wb.z + ub.w * wb.w);
    }
    __syncthreads();
    for (int e = t; e < nkd; e += 512) {
        float acc = 0.0f;
        for (int i = 0; i < n_l; ++i) acc += Uh[i * nkd + e];
        Sv[e] = acc;
    }
    __syncthreads();
    for (int e = t; e < n_l * n_h; e += 512) {
        const int h = e / n_h, k = e - h * n_h;
        float acc = 0.0f;
        for (int l = 0; l < d_h; ++l)
            acc += Uh[h * nkd + k * d_h + l] * Sv[k * d_h + l];
        Av[e] = acc;
    }
    __syncthreads();
    {   // parallel softmax over k: 8 lanes per row h (rows h < n_l)
        const int h = t >> 3, sub = t & 7;
        if (h < n_l) {
            const float invs = 1.0f / 2.8284271247461903f;
            float mx = -1e30f;
            for (int k = sub; k < n_h; k += 8) mx = fmaxf(mx, Av[h * n_h + k]);
            mx = fmaxf(mx, __shfl_xor(mx, 1));
            mx = fmaxf(mx, __shfl_xor(mx, 2));
            mx = fmaxf(mx, __shfl_xor(mx, 4));
            float sum = 0.0f;
            for (int k = sub; k < n_h; k += 8) {
                const float ev = expf((Av[h * n_h + k] - mx) * invs);
                Cv[h * n_h + k] = ev;
                sum += ev;
            }
            sum += __shfl_xor(sum, 1);
            sum += __shfl_xor(sum, 2);
            sum += __shfl_xor(sum, 4);
            const float r = 1.0f / sum;
            for (int k = sub; k < n_h; k += 8) Cv[h * n_h + k] *= r;
        }
    }
    __syncthreads();
    for (int e = t; e < nkd; e += 512) {
        const int k = e / d_h;
        float acc = 0.0f;
        for (int i = 0; i < n_l; ++i) acc += Uh[i * nkd + e] * Cv[i * n_h + k];
        Sv[e] = acc;
    }
    __syncthreads();
    if (t < n_h) {
        float ssq = 0.0f;
        for (int l = 0; l < d_h; ++l) { const float uv = Sv[t * d_h + l]; ssq += uv * uv; }
        const float n = sqrtf(ssq);
        coefs[t] = (1.0f - 1.0f / (expf(n) + 1e-20f)) / (n + 1e-20f);
    }
    if (outG) {
        __syncthreads();
        for (int e = t; e < nkd; e += 512) outG[e] = Sv[e] * coefs[e / d_h];
    }
}

// ---------------- conv1+conv2+conv3+caps fused, one block per image --------
__global__ __launch_bounds__(512, 4) void k_conv2(
    const float* __restrict__ x, const float* __restrict__ w1,
    const float2* __restrict__ sc1, const uint* __restrict__ Bt,
    const float* __restrict__ g,
    const float* __restrict__ bb, const float* __restrict__ bm,
    const float* __restrict__ bv, const float* __restrict__ bias,
    const float* __restrict__ w3T, const float* __restrict__ b3,
    const float* __restrict__ Wr1, const float* __restrict__ Wr2,
    const float* __restrict__ Wr3, float* __restrict__ out) {
    __shared__ __align__(16) uint raw[11552];
    __shared__ __align__(16) float xs[1560];   // [39][40] padded stride
    __shared__ float ured[256];
    const int t = threadIdx.x;
    const int lane = t & 63, wave = t >> 6;          // wave 0..7
    const int ln15 = lane & 15, lq = lane >> 4;
    const int wm = (wave >> 2) * 48;                 // 0 | 48
    const int wn = (wave & 3) * 64;                  // 0 | 64 | 128 | 192
    const int cot_w = (wave & 3) >> 1;               // Bt cot block for this wave
    const int bi = blockIdx.x;

    // stage the input image into padded [39][40] layout (once per image)
    const float* xb = x + (size_t)bi * 1521;
    for (int i = t; i < 1521; i += 512) {
        const int y = i / 39, xc = i - y * 39;
        xs[y * 40 + xc] = xb[i];
    }

    // conv1 thread mapping: qc -> channel pair (2 ch), pg -> positions
    const int qc = t & 15, ol = qc >> 2, qo = (qc & 3) * 2, pg = t >> 4;

    int PE[3], PO[3];
#pragma unroll
    for (int i = 0; i < 3; ++i) {
        const int m = wm + i * 16 + ln15;
        const int p = m < 81 ? m : 80;       // pad rows clamp
        const int oh = p / 9, ow = p - oh * 9;
        PE[i] = lq * 760 + oh * 80 + ow * 4;
        PO[i] = 3040 + lq * 684 + oh * 72 + ow * 4;
    }
    int BRDg[4];
#pragma unroll
    for (int j = 0; j < 4; ++j) {
        const int n = ((wn & 64) + j * 16 + ln15);   // row within cot block
        BRDg[j] = n * 16 + lq * 4;
    }

    f32x4 acc[3][4] = {};

#pragma unroll
    for (int c = 0; c < 4; ++c) {
        // ---- conv1 weight/bn prefetch for this chunk (no LDS dependency) --
        const int o_g = c * 32 + qc * 2;     // global channel of this pair
        float wr[18];
        {
            const float2* wp = reinterpret_cast<const float2*>(w1 + o_g * 9);
#pragma unroll
            for (int q = 0; q < 9; ++q) {
                const float2 wv = wp[q];
                wr[q * 2] = wv.x; wr[q * 2 + 1] = wv.y;
            }
        }
        float2 ssv[2];
        ssv[0] = sc1[o_g];
        ssv[1] = sc1[o_g + 1];

        __syncthreads();   // prev chunk's MFMA reads done (and xs ready at c=0)

        // ---- conv1: 2 channels x ~11 positions into raw (LDS) -------------
        {
            ushort* rawu = (ushort*)raw;
            for (int p = pg; p < 361; p += 32) {
                const int y = p / 19, xq = p - y * 19;
                const int b2 = y * 80 + xq * 2;
                const float2 x01 = *(const float2*)(xs + b2);
                const float  x2v = xs[b2 + 2];
                const float2 x34 = *(const float2*)(xs + b2 + 40);
                const float  x5v = xs[b2 + 42];
                const float2 x67 = *(const float2*)(xs + b2 + 80);
                const float  x8v = xs[b2 + 82];
                uint hw, lw;
                {
                    uint hv[2], lv[2];
#pragma unroll
                    for (int jj = 0; jj < 2; ++jj) {
                        const float a = x01.x * wr[jj * 9 + 0] + x01.y * wr[jj * 9 + 1] +
                                        x2v   * wr[jj * 9 + 2] + x34.x * wr[jj * 9 + 3] +
                                        x34.y * wr[jj * 9 + 4] + x5v   * wr[jj * 9 + 5] +
                                        x67.x * wr[jj * 9 + 6] + x67.y * wr[jj * 9 + 7] +
                                        x8v   * wr[jj * 9 + 8];
                        const float v = fmaxf(fmaf(a, ssv[jj].x, ssv[jj].y), 0.0f);
                        const uint u = __float_as_uint(v);
                        hv[jj] = u >> 16;                               // trunc hi
                        const float d = v - __uint_as_float(u & 0xFFFF0000u);
                        lv[jj] = __float_as_uint(d) >> 16;              // trunc lo
                    }
                    hw = hv[0] | (hv[1] << 16);
                    lw = lv[0] | (lv[1] << 16);
                }
                int ad;
                if ((xq & 1) == 0) {
                    ad = ol * 1520 + (y * 10 + (xq >> 1)) * 8 + qo;
                } else {
                    ad = 6080 + ol * 1368 + (y * 9 + (xq >> 1)) * 8 + qo;
                }
                *(uint*)(rawu + ad)         = hw;
                *(uint*)(rawu + 11552 + ad) = lw;
            }
        }
        __syncthreads();

        // ---- r7 MFMA tap loop: B processed in two j-halves (R18) ---------
#pragma unroll
        for (int tap = 0; tap < 9; ++tap) {
            const int s = c * 9 + tap;
            const int kh = tap / 3, kw = tap - kh * 3;
            const int odd = kw & 1;
            const int sE = kh * 40 + (kw >> 1) * 4;
            const int sO = kh * 36;
            short8 a_h[3], a_l[3];
#pragma unroll
            for (int i = 0; i < 3; ++i) {
                const int addr = odd ? (PO[i] + sO) : (PE[i] + sE);
                a_h[i] = *reinterpret_cast<const short8*>(raw + addr);
                a_l[i] = *reinterpret_cast<const short8*>(raw + addr + 5776);
            }
            const uint* bp = Bt + (size_t)(s * 2 + cot_w) * 4096;
#pragma unroll
            for (int jh = 0; jh < 2; ++jh) {
                uint4 Bc[4];
#pragma unroll
                for (int j2 = 0; j2 < 2; ++j2) {
                    Bc[j2]     = *(const uint4*)(bp + BRDg[jh * 2 + j2]);
                    Bc[2 + j2] = *(const uint4*)(bp + 2048 + BRDg[jh * 2 + j2]);
                }
                short8 bh[2], bl[2];
#pragma unroll
                for (int j2 = 0; j2 < 2; ++j2) {
                    bh[j2] = __builtin_bit_cast(short8, Bc[j2]);
                    bl[j2] = __builtin_bit_cast(short8, Bc[2 + j2]);
                }
#pragma unroll
                for (int i = 0; i < 3; ++i)
#pragma unroll
                    for (int j2 = 0; j2 < 2; ++j2)
                        acc[i][jh * 2 + j2] = __builtin_amdgcn_mfma_f32_16x16x32_bf16(
                            a_h[i], bh[j2], acc[i][jh * 2 + j2], 0, 0, 0);
#pragma unroll
                for (int i = 0; i < 3; ++i)
#pragma unroll
                    for (int j2 = 0; j2 < 2; ++j2)
                        acc[i][jh * 2 + j2] = __builtin_amdgcn_mfma_f32_16x16x32_bf16(
                            a_h[i], bl[j2], acc[i][jh * 2 + j2], 0, 0, 0);
#pragma unroll
                for (int i = 0; i < 3; ++i)
#pragma unroll
                    for (int j2 = 0; j2 < 2; ++j2)
                        acc[i][jh * 2 + j2] = __builtin_amdgcn_mfma_f32_16x16x32_bf16(
                            a_l[i], bh[j2], acc[i][jh * 2 + j2], 0, 0, 0);
            }
        }
    }

    // ---- epilogue: bn + relu + fused depthwise conv3 reduction ------------
    float scj[4], shj[4];
#pragma unroll
    for (int j = 0; j < 4; ++j) {
        const int co = wn + j * 16 + ln15;
        const float inv = g[co] * rsqrtf(bv[co] + 1e-5f);
        scj[j] = inv;
        shj[j] = bias[co] * inv + bb[co] - bm[co] * inv;
    }
    float usum[4] = {0.f, 0.f, 0.f, 0.f};
#pragma unroll
    for (int i = 0; i < 3; ++i)
#pragma unroll
        for (int r = 0; r < 4; ++r) {
            const int m = wm + i * 16 + lq * 4 + r;
            if (m < 81) {
                const float* wrow = w3T + m * 256;
#pragma unroll
                for (int j = 0; j < 4; ++j) {
                    const int col = wn + j * 16 + ln15;
                    const float v = fmaxf(fmaf(acc[i][j][r], scj[j], shj[j]), 0.0f);
                    usum[j] = fmaf(v, wrow[col], usum[j]);
                }
            }
        }
#pragma unroll
    for (int j = 0; j < 4; ++j) {
        usum[j] += __shfl_xor(usum[j], 16);
        usum[j] += __shfl_xor(usum[j], 32);
    }
    if (lq == 0 && wm == 0) {
#pragma unroll
        for (int j = 0; j < 4; ++j) ured[wn + j * 16 + ln15] = usum[j];
    }
    __syncthreads();   // ured ready; tap-loop reads of raw long done

    // ---- caps scratch aliased onto raw ------------------------------------
    float* cF    = (float*)raw;          // capsU: [0,256)
    float* Uh    = cF + 256;             // [256, 8448)
    float* Sv    = cF + 8448;            // [8448, 8704)
    float* Av    = cF + 8704;            // [8704, 9728)
    float* Cv    = cF + 9728;            // [9728, 10752)
    float* coefs = cF + 10752;           // [10752, 10784)

    if (lq == 0 && wm == 48) {
#pragma unroll
        for (int j = 0; j < 4; ++j) {
            const int col = wn + j * 16 + ln15;
            cF[col] = usum[j] + ured[col] + b3[col];
        }
    }
    __syncthreads();
    if (t < 32) {   // initial squash coefs over 32 caps of 8 (scaling folded)
        float ssq = 0.0f;
        for (int j = 0; j < 8; ++j) { const float uv = cF[t * 8 + j]; ssq += uv * uv; }
        const float n = sqrtf(ssq);
        coefs[t] = (1.0f - 1.0f / (expf(n) + 1e-20f)) / (n + 1e-20f);
    }

    fccaps512(32, 32,  8, Wr1, cF, coefs, Uh, Sv, Av, Cv, coefs, nullptr, t);
    fccaps512(32, 32,  8, Wr2, Sv, coefs, Uh, Sv, Av, Cv, coefs, nullptr, t);
    fccaps512(32, 10, 16, Wr3, Sv, coefs, Uh, Sv, Av, Cv, coefs,
              out + (size_t)bi * 160, t);
}

// ---------------------------------------------------------------------------
extern "C" void kernel_launch(void* const* d_in, const int* in_sizes, int n_in,
                              void* d_out, int out_size, void* d_ws, size_t ws_size,
                              hipStream_t stream) {
    const float* x    = (const float*)d_in[0];
    const float* c1w  = (const float*)d_in[1];
    const float* c1b  = (const float*)d_in[2];
    const float* bn1g = (const float*)d_in[3];
    const float* bn1b = (const float*)d_in[4];
    const float* bn1m = (const float*)d_in[5];
    const float* bn1v = (const float*)d_in[6];
    const float* c2w  = (const float*)d_in[7];
    const float* c2b  = (const float*)d_in[8];
    const float* bn2g = (const float*)d_in[9];
    const float* bn2b = (const float*)d_in[10];
    const float* bn2m = (const float*)d_in[11];
    const float* bn2v = (const float*)d_in[12];
    const float* c3w  = (const float*)d_in[13];
    const float* c3b  = (const float*)d_in[14];
    const float* W1   = (const float*)d_in[15];
    const float* W2   = (const float*)d_in[16];
    const float* W3   = (const float*)d_in[17];
    float* out = (float*)d_out;
    uint*  wsu = (uint*)d_ws;
    float* wsf = (float*)d_ws;

    uint*   Bt  = wsu + 131072;            //    294,912 dw
    float*  w3T = wsf + 425984;            //     20,736 dw
    float*  Wr1 = wsf + 446720;            //     65,536 dw
    float*  Wr2 = wsf + 512256;            //     65,536 dw
    float*  Wr3 = wsf + 577792;            //     40,960 dw
    float2* sc1 = (float2*)(wsf + 618752); //        256 dw

    k_prep<<<dim3(322), 256, 0, stream>>>(c2w, Bt, c3w, w3T, W1, W2, W3,
                                          Wr1, Wr2, Wr3,
                                          c1b, bn1g, bn1b, bn1m, bn1v, sc1);
    k_conv2<<<dim3(512), 512, 0, stream>>>(x, c1w, sc1, Bt,
                                           bn2g, bn2b, bn2m, bn2v,
                                           c2b, w3T, c3b, Wr1, Wr2, Wr3, out);
}